// Round 7
// baseline (388.726 us; speedup 1.0000x reference)
//
#include <hip/hip_runtime.h>

// NonLocalAttention n=4, c=64, hw=6400.
// conv (MFMA bf16 hi/lo-compensated) -> bf16 Q(log2e-scaled)[n,p,c],
// K[n,p,c], V[n,c,p].
// Split-K flash attention (grid 25x4x10, 256q/block, 64q/wave):
//  - K/V tiles staged via global_load_lds (width 16) into XOR-swizzled flat
//    LDS tiles (s = r*8 + (c8 ^ (r&7))): no staging VGPRs, no ds_writes,
//    fragment ds_read_b128s spread over all 8 bank-quads (conflict-free).
//  - S^T = mfma(K,Q); S->PV fused per 32-key half; PV A-frags via lane^32
//    quad exchange (validated R5/R6). No softmax shift: uniform exp2 scale
//    cancels in the final O/l division; fp32 holds the dynamic range.
//  - ONE barrier per iter, double-buffered 8KB tiles, 32KB LDS total.
//  - __launch_bounds__(256,3): target 3 waves/SIMD (R5 was reg-capped at 2).
// bf16 partial O + fp32 partial l -> combine kernel.

typedef __attribute__((ext_vector_type(8))) unsigned short us8;
typedef __attribute__((ext_vector_type(4))) unsigned short us4;
typedef __attribute__((ext_vector_type(8))) __bf16 bf16x8;
typedef __attribute__((ext_vector_type(16))) float f32x16;

#define HW 6400
#define L2E 1.44269504088896340736f
#define KS 10
#define ITERS 10  // (HW/64)/KS

union V8 { us8 s; us4 h[2]; bf16x8 b; unsigned u4[4]; };

__device__ __forceinline__ unsigned short f32_to_bf16(float f) {
  unsigned u = __float_as_uint(f);
  u += 0x7fffu + ((u >> 16) & 1u);  // RNE; finite inputs
  return (unsigned short)(u >> 16);
}
__device__ __forceinline__ float bf16_bits_to_f32(unsigned short u) {
  return __uint_as_float(((unsigned)u) << 16);
}
__device__ __forceinline__ unsigned pack_bf16x2(float a, float b) {
#if __has_builtin(__builtin_amdgcn_cvt_pk_bf16_f32)
  auto v = __builtin_amdgcn_cvt_pk_bf16_f32(a, b);
  unsigned u;
  __builtin_memcpy(&u, &v, 4);
  return u;
#else
  unsigned ua = __float_as_uint(a); ua += 0x7fffu + ((ua >> 16) & 1u);
  unsigned ub = __float_as_uint(b); ub += 0x7fffu + ((ub >> 16) & 1u);
  return (ua >> 16) | (ub & 0xffff0000u);
#endif
}

// async global->LDS, 16B per lane; LDS dest = wave-uniform base + lane*16
__device__ __forceinline__ void glds16(const void* g, void* l) {
  __builtin_amdgcn_global_load_lds(
      (const __attribute__((address_space(1))) void*)g,
      (__attribute__((address_space(3))) void*)l, 16, 0, 0);
}

// split 8 fp32 -> bf16 hi fragment + bf16 lo (residual) fragment
__device__ __forceinline__ void split_hilo(const float* f, V8& hi, V8& lo) {
#pragma unroll
  for (int j = 0; j < 8; ++j) {
    const unsigned short h = f32_to_bf16(f[j]);
    const float r = f[j] - bf16_bits_to_f32(h);
    hi.s[j] = h;
    lo.s[j] = f32_to_bf16(r);
  }
}

// ---------------------------------------------------------------------------
// Conv via MFMA: grid (50, 4) x 256 thr. Block = one n, 128 pixels, 3 convs.
// (Wh+Wl)(Xh+Xl) with 3 MFMAs per tile -> fp32-equivalent accuracy.
// (Unchanged from R5 — conv is not the lever; total-attn has been ~78 us
//  fixed across three different conv implementations.)
// ---------------------------------------------------------------------------
__global__ __launch_bounds__(256, 2) void conv_kernel(
    const float* __restrict__ x,
    const float* __restrict__ w1, const float* __restrict__ b1,
    const float* __restrict__ w2, const float* __restrict__ b2,
    const float* __restrict__ w3, const float* __restrict__ b3,
    unsigned short* __restrict__ Qg, unsigned short* __restrict__ Kg,
    unsigned short* __restrict__ Vg) {
  __shared__ __align__(16) float xs[64 * 132];           // X tile fp32
  __shared__ __align__(16) unsigned short tb[128 * 72];  // [p][c] transpose buf

  const int t = threadIdx.x;
  const int n = blockIdx.y;
  const int p0 = blockIdx.x * 128;
  const int wv = t >> 6;
  const int lane = t & 63;
  const int l31 = lane & 31;
  const int lh = lane >> 5;
  const int ob = (wv & 1) * 32;   // o-row base
  const int pw = (wv >> 1) * 64;  // pixel base within block

  {  // stage X tile [64 c][128 p] fp32
    const int c = t >> 2, qq = t & 3;
    const float* src = x + ((size_t)(n * 64 + c) * HW + p0 + qq * 32);
    float* dst = xs + c * 132 + qq * 32;
#pragma unroll
    for (int i = 0; i < 8; ++i)
      *(float4*)(dst + i * 4) = *(const float4*)(src + i * 4);
  }
  __syncthreads();

  const float* wms[3] = {w1, w2, w3};
  const float* bms[3] = {b1, b2, b3};

#pragma unroll 1
  for (int k = 0; k < 3; ++k) {
    const float* wm = wms[k];
    const float* bm = bms[k];

    V8 ah[4], al[4];
#pragma unroll
    for (int kst = 0; kst < 4; ++kst) {
      const float* wr = wm + (size_t)(ob + l31) * 64 + kst * 16 + lh * 8;
      float wf[8];
      *(float4*)(wf) = *(const float4*)wr;
      *(float4*)(wf + 4) = *(const float4*)(wr + 4);
      split_hilo(wf, ah[kst], al[kst]);
    }

    f32x16 acc[2];
#pragma unroll
    for (int pb = 0; pb < 2; ++pb)
#pragma unroll
      for (int r = 0; r < 16; ++r) acc[pb][r] = 0.f;

#pragma unroll
    for (int kst = 0; kst < 4; ++kst) {
#pragma unroll
      for (int pb = 0; pb < 2; ++pb) {
        float xf[8];
        const float* xp = xs + (kst * 16 + lh * 8) * 132 + pw + pb * 32 + l31;
#pragma unroll
        for (int j = 0; j < 8; ++j) xf[j] = xp[j * 132];
        V8 bh, bl;
        split_hilo(xf, bh, bl);
        acc[pb] = __builtin_amdgcn_mfma_f32_32x32x16_bf16(al[kst].b, bh.b, acc[pb], 0, 0, 0);
        acc[pb] = __builtin_amdgcn_mfma_f32_32x32x16_bf16(ah[kst].b, bl.b, acc[pb], 0, 0, 0);
        acc[pb] = __builtin_amdgcn_mfma_f32_32x32x16_bf16(ah[kst].b, bh.b, acc[pb], 0, 0, 0);
      }
    }

    if (k < 2) {  // Q or K: transpose to [p][c] via LDS, then coalesced store
#pragma unroll
      for (int pb = 0; pb < 2; ++pb) {
#pragma unroll
        for (int rq = 0; rq < 4; ++rq) {
          const int o = ob + 8 * rq + 4 * lh;
          const int pcol = pw + pb * 32 + l31;
          float v[4];
#pragma unroll
          for (int j = 0; j < 4; ++j) {
            float a = acc[pb][4 * rq + j] + bm[o + j];
            a = fmaxf(a, 0.f) + 0.2f * fminf(a, 0.f);
            if (k == 0) a *= L2E;
            v[j] = a;
          }
          unsigned* dst = (unsigned*)(tb + pcol * 72 + o);
          dst[0] = pack_bf16x2(v[0], v[1]);
          dst[1] = pack_bf16x2(v[2], v[3]);
        }
      }
      __syncthreads();
      {
        const int p = t >> 1, half = t & 1;
        const unsigned short* src = tb + p * 72 + half * 32;
        unsigned short* dst = (k == 0 ? Qg : Kg) +
                              (size_t)(n * HW + p0 + p) * 64 + half * 32;
#pragma unroll
        for (int i = 0; i < 4; ++i) *(us8*)(dst + i * 8) = *(const us8*)(src + i * 8);
      }
      __syncthreads();  // tb reused by next conv
    } else {  // V [n,c,p]: direct coalesced 2B stores
#pragma unroll
      for (int pb = 0; pb < 2; ++pb) {
#pragma unroll
        for (int r = 0; r < 16; ++r) {
          const int o = ob + 8 * (r >> 2) + 4 * lh + (r & 3);
          const int pcol = pw + pb * 32 + l31;
          float a = acc[pb][r] + bm[o];
          a = fmaxf(a, 0.f) + 0.2f * fminf(a, 0.f);
          Vg[(size_t)(n * 64 + o) * HW + p0 + pcol] = f32_to_bf16(a);
        }
      }
    }
  }
}

// ---------------------------------------------------------------------------
// Split-K flash attention: grid (25, 4, KS) x 256 thr (4 waves).
// LDS: K0|K1|V0|V1, 8KB each (flat, XOR-swizzled), 32KB total.
// Tile layout: 16B block s holds (row r = s>>3, chunk c8 = (s&7)^(r&7)).
// Fragment read (row r, chunk q) -> byte offset r*128 + ((q^(r&7))<<4):
// for fixed q, s%8 spans all 8 bank-quads uniformly -> conflict-free b128.
// ---------------------------------------------------------------------------
__global__ __launch_bounds__(256, 3) void attn_kernel(
    const unsigned short* __restrict__ Qg, const unsigned short* __restrict__ Kg,
    const unsigned short* __restrict__ Vg, unsigned short* __restrict__ Opart,
    float* __restrict__ Lpart) {
  __shared__ __align__(16) char smem[32768];
  unsigned short* Otb = (unsigned short*)smem;  // [64][132] bf16 epilogue overlay

  const int t = threadIdx.x;
  const int w = t >> 6;
  const int lane = t & 63;
  const int l31 = lane & 31;
  const int lh = lane >> 5;
  const int nb = blockIdx.y;
  const int qb = blockIdx.x * 256;
  const int ks = blockIdx.z;
  const int key0 = ks * (HW / KS);

  // loop-invariant Q fragments (B operand: col m = l31)
  V8 aQ[2][4];
#pragma unroll
  for (int qh = 0; qh < 2; ++qh) {
    const unsigned short* qrow =
        Qg + (size_t)(nb * HW + qb + w * 64 + qh * 32 + l31) * 64 + lh * 8;
#pragma unroll
    for (int kst = 0; kst < 4; ++kst) aQ[qh][kst].s = *(const us8*)(qrow + kst * 16);
  }

  // swizzled LDS fragment-read byte offsets (same for K and V tiles)
  int qx[4];
  {
    const int x7 = l31 & 7;
#pragma unroll
    for (int kst = 0; kst < 4; ++kst)
      qx[kst] = l31 * 128 + (((kst * 2 + lh) ^ x7) << 4);
  }

  // per-lane global source addresses for global_load_lds (16B per lane).
  // lane covers LDS block s = w*64 + lane (call0) / +256 (call1):
  // r_local = w*8 + (lane>>3), c8 = (lane&7) ^ (lane>>3)  [(w*8)&7 == 0]
  const int r8 = lane >> 3;
  const int c8 = (lane & 7) ^ r8;
  const char* kg = (const char*)Kg + ((size_t)(nb * HW + key0) + w * 8 + r8) * 128 +
                   c8 * 16;
  const char* vg = (const char*)Vg + ((size_t)nb * 64 * HW + key0) * 2 +
                   (size_t)(w * 8 + r8) * (HW * 2) + c8 * 16;

  f32x16 accO[2][2];
#pragma unroll
  for (int qh = 0; qh < 2; ++qh)
#pragma unroll
    for (int ci = 0; ci < 2; ++ci)
#pragma unroll
      for (int r = 0; r < 16; ++r) accO[qh][ci][r] = 0.f;
  float lp[2] = {0.f, 0.f};

  {  // stage tile 0 into buffer 0
    char* kl = smem + w * 1024;
    char* vl = smem + 16384 + w * 1024;
    glds16(kg, kl);
    glds16(kg + 4096, kl + 4096);          // rows 32..63 (K: +32*128B)
    glds16(vg, vl);
    glds16(vg + (size_t)32 * HW * 2, vl + 4096);  // c rows 32..63
  }
  __syncthreads();

  auto body = [&](int jt, int b) {
    {  // prefetch tile jt+1 into buffer 1-b (tail over-read stays in ws,
       // never consumed)
      const char* kp = kg + (size_t)(jt + 1) * 8192;
      const char* vp = vg + (size_t)(jt + 1) * 128;
      char* kl = smem + (1 - b) * 8192 + w * 1024;
      char* vl = smem + 16384 + (1 - b) * 8192 + w * 1024;
      glds16(kp, kl);
      glds16(kp + 4096, kl + 4096);
      glds16(vp, vl);
      glds16(vp + (size_t)32 * HW * 2, vl + 4096);
    }
    const char* Kc = smem + b * 8192;
    const char* Vc = smem + 16384 + b * 8192;

#pragma unroll
    for (int ni = 0; ni < 2; ++ni) {
      // S-phase: K frags read once, used by both q-halves
      V8 ak[4];
#pragma unroll
      for (int kst = 0; kst < 4; ++kst)
        ak[kst].s = *(const us8*)(Kc + ni * 4096 + qx[kst]);

      uint2 pkg[2][4];  // [qh][g]: keys ni*32+8g+4lh+{0..3}, q-col l31
#pragma unroll
      for (int qh = 0; qh < 2; ++qh) {
        f32x16 sacc;
#pragma unroll
        for (int r = 0; r < 16; ++r) sacc[r] = 0.f;
#pragma unroll
        for (int kst = 0; kst < 4; ++kst)
          sacc = __builtin_amdgcn_mfma_f32_32x32x16_bf16(ak[kst].b,
                                                         aQ[qh][kst].b, sacc, 0, 0, 0);
#pragma unroll
        for (int g = 0; g < 4; ++g) {
          const float p0 = __builtin_amdgcn_exp2f(sacc[4 * g + 0]);
          const float p1 = __builtin_amdgcn_exp2f(sacc[4 * g + 1]);
          const float p2 = __builtin_amdgcn_exp2f(sacc[4 * g + 2]);
          const float p3 = __builtin_amdgcn_exp2f(sacc[4 * g + 3]);
          lp[qh] += (p0 + p1) + (p2 + p3);
          pkg[qh][g].x = pack_bf16x2(p0, p1);
          pkg[qh][g].y = pack_bf16x2(p2, p3);
        }
      }

      // PV-phase: V frags for keys ni*32..+31 (chunk index kst_pv = 2ni+kk)
      V8 bv[2][2];
#pragma unroll
      for (int ci = 0; ci < 2; ++ci)
#pragma unroll
        for (int kk = 0; kk < 2; ++kk)
          bv[ci][kk].s = *(const us8*)(Vc + ci * 4096 + qx[2 * ni + kk]);

#pragma unroll
      for (int qh = 0; qh < 2; ++qh) {
#pragma unroll
        for (int kk = 0; kk < 2; ++kk) {
          const int gb = 2 * kk;
          const uint2 qa = pkg[qh][gb];
          const uint2 qb2 = pkg[qh][gb + 1];
          uint2 send;
          send.x = lh ? qa.x : qb2.x;
          send.y = lh ? qa.y : qb2.y;
          uint2 recv;
          recv.x = __shfl_xor(send.x, 32);
          recv.y = __shfl_xor(send.y, 32);
          const uint2 keep = {lh ? qb2.x : qa.x, lh ? qb2.y : qa.y};
          V8 ap;
          ap.u4[0] = lh ? recv.x : keep.x;
          ap.u4[1] = lh ? recv.y : keep.y;
          ap.u4[2] = lh ? keep.x : recv.x;
          ap.u4[3] = lh ? keep.y : recv.y;
          accO[qh][0] = __builtin_amdgcn_mfma_f32_32x32x16_bf16(
              ap.b, bv[0][kk].b, accO[qh][0], 0, 0, 0);
          accO[qh][1] = __builtin_amdgcn_mfma_f32_32x32x16_bf16(
              ap.b, bv[1][kk].b, accO[qh][1], 0, 0, 0);
        }
      }
    }
    __syncthreads();  // drains prefetch (vmcnt) + orders buffer reuse
  };

#pragma unroll 1
  for (int jt = 0; jt < ITERS; jt += 2) {
    body(jt, 0);
    body(jt + 1, 1);
  }

  // l reduce + store
#pragma unroll
  for (int qh = 0; qh < 2; ++qh) {
    const float lsum = lp[qh] + __shfl_xor(lp[qh], 32);
    if (lh == 0)
      Lpart[((size_t)ks * 4 + nb) * HW + qb + w * 64 + qh * 32 + l31] = lsum;
  }

  // epilogue: two 128-q passes through Otb[64][132] bf16; coalesced us8 stores.
#pragma unroll 1
  for (int pi = 0; pi < 2; ++pi) {
    __syncthreads();
    if ((w >> 1) == pi) {
#pragma unroll
      for (int qh = 0; qh < 2; ++qh)
#pragma unroll
        for (int ci = 0; ci < 2; ++ci)
#pragma unroll
          for (int r = 0; r < 16; ++r) {
            const int qcol = (w & 1) * 64 + qh * 32 + 8 * (r >> 2) + 4 * lh + (r & 3);
            Otb[(ci * 32 + l31) * 132 + qcol] = f32_to_bf16(accO[qh][ci][r]);
          }
    }
    __syncthreads();
    {
      const int ch = t >> 2, part = t & 3;
      const unsigned short* src = Otb + ch * 132 + part * 32;
      unsigned short* dst = Opart + (((size_t)ks * 4 + nb) * 64 + ch) * HW +
                            qb + pi * 128 + part * 32;
#pragma unroll
      for (int i = 0; i < 4; ++i) {
        V8 v;
        v.h[0] = *(const us4*)(src + i * 8);
        v.h[1] = *(const us4*)(src + i * 8 + 4);
        *(us8*)(dst + i * 8) = v.s;
      }
    }
  }
}

// ---------------------------------------------------------------------------
// Combine: out[n][c][p] = sum_ks O[ks][n][c][p] / sum_ks l[ks][n][p].
// ---------------------------------------------------------------------------
__global__ __launch_bounds__(256) void combine_kernel(
    const unsigned short* __restrict__ Opart, const float* __restrict__ Lpart,
    float* __restrict__ out) {
  const int tid = blockIdx.x * 256 + threadIdx.x;
  const size_t e = (size_t)tid * 4;
  float4 o = {0.f, 0.f, 0.f, 0.f};
#pragma unroll
  for (int ks = 0; ks < KS; ++ks) {
    const us4 v = *(const us4*)(Opart + (size_t)ks * (4 * 64 * HW) + e);
    o.x += bf16_bits_to_f32(v[0]);
    o.y += bf16_bits_to_f32(v[1]);
    o.z += bf16_bits_to_f32(v[2]);
    o.w += bf16_bits_to_f32(v[3]);
  }
  const int n = (int)(e / (64 * HW));
  const int p = (int)(e % HW);
  float4 l = {0.f, 0.f, 0.f, 0.f};
#pragma unroll
  for (int ks = 0; ks < KS; ++ks) {
    const float4 v = *(const float4*)(Lpart + ((size_t)ks * 4 + n) * HW + p);
    l.x += v.x; l.y += v.y; l.z += v.z; l.w += v.w;
  }
  float4 r;
  r.x = o.x / l.x; r.y = o.y / l.y; r.z = o.z / l.z; r.w = o.w / l.w;
  *(float4*)(out + e) = r;
}

extern "C" void kernel_launch(void* const* d_in, const int* in_sizes, int n_in,
                              void* d_out, int out_size, void* d_ws, size_t ws_size,
                              hipStream_t stream) {
  const float* x = (const float*)d_in[0];
  const float* w1 = (const float*)d_in[1];
  const float* b1 = (const float*)d_in[2];
  const float* w2 = (const float*)d_in[3];
  const float* b2 = (const float*)d_in[4];
  const float* w3 = (const float*)d_in[5];
  const float* b3 = (const float*)d_in[6];
  float* out = (float*)d_out;

  // ws: Q,K,V bf16 (9.8 MB) + Opart bf16 KS=10 (32.8 MB) + Lpart (1.0 MB)
  unsigned short* Q = (unsigned short*)d_ws;
  unsigned short* K = Q + (size_t)4 * HW * 64;
  unsigned short* V = K + (size_t)4 * HW * 64;
  unsigned short* Opart = V + (size_t)4 * HW * 64;
  float* Lpart = (float*)(Opart + (size_t)KS * 4 * 64 * HW);

  conv_kernel<<<dim3(50, 4), 256, 0, stream>>>(x, w1, b1, w2, b2, w3, b3,
                                               Q, K, V);
  attn_kernel<<<dim3(25, 4, KS), 256, 0, stream>>>(Q, K, V, Opart, Lpart);
  combine_kernel<<<1600, 256, 0, stream>>>(Opart, Lpart, out);
}

// Round 8
// 150.676 us; speedup vs baseline: 2.5799x; 2.5799x over previous
//
#include <hip/hip_runtime.h>

// NonLocalAttention n=4, c=64, hw=6400.
// conv (MFMA bf16 hi/lo-compensated) -> bf16 Q(log2e-scaled)[n,p,c],
// K[n,p,c], V[n,c,p].
// Split-K flash attention, LEAN-WAVE shape: grid (50,4,5), 128q/block,
// 32q/wave -> ~64 VGPR + 32 AGPR per wave (R3-proven register shape),
// 4 blocks/CU x 4 waves resident. R5-proven pitch-72 LDS staging (b128
// conflict-free), R6-proven S->PV fusion per 32-key half, lane^32 quad
// exchange for PV A-frags. No softmax shift (uniform exp2 scale cancels in
// the final O/l division; fp32 holds the range). ONE barrier/iter.
// bf16 partial O + fp32 partial l -> combine kernel.

typedef __attribute__((ext_vector_type(8))) unsigned short us8;
typedef __attribute__((ext_vector_type(4))) unsigned short us4;
typedef __attribute__((ext_vector_type(8))) __bf16 bf16x8;
typedef __attribute__((ext_vector_type(16))) float f32x16;

#define HW 6400
#define L2E 1.44269504088896340736f
#define KS 5
#define ITERS 20  // (HW/64)/KS

union V8 { us8 s; us4 h[2]; bf16x8 b; unsigned u4[4]; };

__device__ __forceinline__ unsigned short f32_to_bf16(float f) {
  unsigned u = __float_as_uint(f);
  u += 0x7fffu + ((u >> 16) & 1u);  // RNE; finite inputs
  return (unsigned short)(u >> 16);
}
__device__ __forceinline__ float bf16_bits_to_f32(unsigned short u) {
  return __uint_as_float(((unsigned)u) << 16);
}
__device__ __forceinline__ unsigned pack_bf16x2(float a, float b) {
#if __has_builtin(__builtin_amdgcn_cvt_pk_bf16_f32)
  auto v = __builtin_amdgcn_cvt_pk_bf16_f32(a, b);
  unsigned u;
  __builtin_memcpy(&u, &v, 4);
  return u;
#else
  unsigned ua = __float_as_uint(a); ua += 0x7fffu + ((ua >> 16) & 1u);
  unsigned ub = __float_as_uint(b); ub += 0x7fffu + ((ub >> 16) & 1u);
  return (ua >> 16) | (ub & 0xffff0000u);
#endif
}

// split 8 fp32 -> bf16 hi fragment + bf16 lo (residual) fragment
__device__ __forceinline__ void split_hilo(const float* f, V8& hi, V8& lo) {
#pragma unroll
  for (int j = 0; j < 8; ++j) {
    const unsigned short h = f32_to_bf16(f[j]);
    const float r = f[j] - bf16_bits_to_f32(h);
    hi.s[j] = h;
    lo.s[j] = f32_to_bf16(r);
  }
}

// ---------------------------------------------------------------------------
// Conv via MFMA: grid (50, 4) x 256 thr. Block = one n, 128 pixels, 3 convs.
// (Wh+Wl)(Xh+Xl) with 3 MFMAs per tile -> fp32-equivalent accuracy.
// UNCHANGED from R5 (proven; conv is not the lever).
// ---------------------------------------------------------------------------
__global__ __launch_bounds__(256, 2) void conv_kernel(
    const float* __restrict__ x,
    const float* __restrict__ w1, const float* __restrict__ b1,
    const float* __restrict__ w2, const float* __restrict__ b2,
    const float* __restrict__ w3, const float* __restrict__ b3,
    unsigned short* __restrict__ Qg, unsigned short* __restrict__ Kg,
    unsigned short* __restrict__ Vg) {
  __shared__ __align__(16) float xs[64 * 132];           // X tile fp32
  __shared__ __align__(16) unsigned short tb[128 * 72];  // [p][c] transpose buf

  const int t = threadIdx.x;
  const int n = blockIdx.y;
  const int p0 = blockIdx.x * 128;
  const int wv = t >> 6;
  const int lane = t & 63;
  const int l31 = lane & 31;
  const int lh = lane >> 5;
  const int ob = (wv & 1) * 32;   // o-row base
  const int pw = (wv >> 1) * 64;  // pixel base within block

  {  // stage X tile [64 c][128 p] fp32
    const int c = t >> 2, qq = t & 3;
    const float* src = x + ((size_t)(n * 64 + c) * HW + p0 + qq * 32);
    float* dst = xs + c * 132 + qq * 32;
#pragma unroll
    for (int i = 0; i < 8; ++i)
      *(float4*)(dst + i * 4) = *(const float4*)(src + i * 4);
  }
  __syncthreads();

  const float* wms[3] = {w1, w2, w3};
  const float* bms[3] = {b1, b2, b3};

#pragma unroll 1
  for (int k = 0; k < 3; ++k) {
    const float* wm = wms[k];
    const float* bm = bms[k];

    V8 ah[4], al[4];
#pragma unroll
    for (int kst = 0; kst < 4; ++kst) {
      const float* wr = wm + (size_t)(ob + l31) * 64 + kst * 16 + lh * 8;
      float wf[8];
      *(float4*)(wf) = *(const float4*)wr;
      *(float4*)(wf + 4) = *(const float4*)(wr + 4);
      split_hilo(wf, ah[kst], al[kst]);
    }

    f32x16 acc[2];
#pragma unroll
    for (int pb = 0; pb < 2; ++pb)
#pragma unroll
      for (int r = 0; r < 16; ++r) acc[pb][r] = 0.f;

#pragma unroll
    for (int kst = 0; kst < 4; ++kst) {
#pragma unroll
      for (int pb = 0; pb < 2; ++pb) {
        float xf[8];
        const float* xp = xs + (kst * 16 + lh * 8) * 132 + pw + pb * 32 + l31;
#pragma unroll
        for (int j = 0; j < 8; ++j) xf[j] = xp[j * 132];
        V8 bh, bl;
        split_hilo(xf, bh, bl);
        acc[pb] = __builtin_amdgcn_mfma_f32_32x32x16_bf16(al[kst].b, bh.b, acc[pb], 0, 0, 0);
        acc[pb] = __builtin_amdgcn_mfma_f32_32x32x16_bf16(ah[kst].b, bl.b, acc[pb], 0, 0, 0);
        acc[pb] = __builtin_amdgcn_mfma_f32_32x32x16_bf16(ah[kst].b, bh.b, acc[pb], 0, 0, 0);
      }
    }

    if (k < 2) {  // Q or K: transpose to [p][c] via LDS, then coalesced store
#pragma unroll
      for (int pb = 0; pb < 2; ++pb) {
#pragma unroll
        for (int rq = 0; rq < 4; ++rq) {
          const int o = ob + 8 * rq + 4 * lh;
          const int pcol = pw + pb * 32 + l31;
          float v[4];
#pragma unroll
          for (int j = 0; j < 4; ++j) {
            float a = acc[pb][4 * rq + j] + bm[o + j];
            a = fmaxf(a, 0.f) + 0.2f * fminf(a, 0.f);
            if (k == 0) a *= L2E;
            v[j] = a;
          }
          unsigned* dst = (unsigned*)(tb + pcol * 72 + o);
          dst[0] = pack_bf16x2(v[0], v[1]);
          dst[1] = pack_bf16x2(v[2], v[3]);
        }
      }
      __syncthreads();
      {
        const int p = t >> 1, half = t & 1;
        const unsigned short* src = tb + p * 72 + half * 32;
        unsigned short* dst = (k == 0 ? Qg : Kg) +
                              (size_t)(n * HW + p0 + p) * 64 + half * 32;
#pragma unroll
        for (int i = 0; i < 4; ++i) *(us8*)(dst + i * 8) = *(const us8*)(src + i * 8);
      }
      __syncthreads();  // tb reused by next conv
    } else {  // V [n,c,p]: direct coalesced 2B stores
#pragma unroll
      for (int pb = 0; pb < 2; ++pb) {
#pragma unroll
        for (int r = 0; r < 16; ++r) {
          const int o = ob + 8 * (r >> 2) + 4 * lh + (r & 3);
          const int pcol = pw + pb * 32 + l31;
          float a = acc[pb][r] + bm[o];
          a = fmaxf(a, 0.f) + 0.2f * fminf(a, 0.f);
          Vg[(size_t)(n * 64 + o) * HW + p0 + pcol] = f32_to_bf16(a);
        }
      }
    }
  }
}

// ---------------------------------------------------------------------------
// Split-K flash attention: grid (50, 4, KS) x 256 thr (4 waves).
// Wave = 32 q; 64 keys/iter; ITERS iters over this block's key chunk.
// LDS: double-buffered K,V tiles [64][72] bf16 = 36864 B (R5-proven layout).
// Register shape: aQ 16 + staging 16 + transient ak/bv/sacc + accO 32 AGPR.
// ---------------------------------------------------------------------------
__global__ __launch_bounds__(256, 4) void attn_kernel(
    const unsigned short* __restrict__ Qg, const unsigned short* __restrict__ Kg,
    const unsigned short* __restrict__ Vg, unsigned short* __restrict__ Opart,
    float* __restrict__ Lpart) {
  __shared__ __align__(16) char smem[36864];
  // K buffers at 0 / 9216; V buffers at 18432 / 27648 (each [64][72] bf16)
  unsigned short* Otb = (unsigned short*)smem;  // [64][132] bf16 epilogue overlay

  const int t = threadIdx.x;
  const int w = t >> 6;
  const int lane = t & 63;
  const int l31 = lane & 31;
  const int lh = lane >> 5;
  const int nb = blockIdx.y;
  const int qb = blockIdx.x * 128;
  const int ks = blockIdx.z;
  const int key0 = ks * (HW / KS);

  // loop-invariant Q fragments from global (B operand: col m = l31)
  V8 aQ[4];
  {
    const unsigned short* qrow =
        Qg + (size_t)(nb * HW + qb + w * 32 + l31) * 64 + lh * 8;
#pragma unroll
    for (int kst = 0; kst < 4; ++kst) aQ[kst].s = *(const us8*)(qrow + kst * 16);
  }

  f32x16 accO[2];
#pragma unroll
  for (int ci = 0; ci < 2; ++ci)
#pragma unroll
    for (int r = 0; r < 16; ++r) accO[ci][r] = 0.f;
  float lp = 0.f;

  const int soff = (t >> 2) * 72 + (t & 3) * 16;
  const unsigned short* ksrc =
      Kg + (size_t)nb * HW * 64 + (size_t)(key0 + (t >> 2)) * 64 + (t & 3) * 16;
  const unsigned short* vsrc =
      Vg + (size_t)nb * 64 * HW + (size_t)(t >> 2) * HW + key0 + (t & 3) * 16;

  V8 kr0, kr1, vr0, vr1;
  kr0.s = *(const us8*)ksrc;
  kr1.s = *(const us8*)(ksrc + 8);
  vr0.s = *(const us8*)vsrc;
  vr1.s = *(const us8*)(vsrc + 8);
  {  // tile 0 -> buffer 0
    unsigned short* kd = (unsigned short*)smem + soff;
    unsigned short* vd = (unsigned short*)(smem + 18432) + soff;
    *(us8*)kd = kr0.s; *(us8*)(kd + 8) = kr1.s;
    *(us8*)vd = vr0.s; *(us8*)(vd + 8) = vr1.s;
  }
  __syncthreads();

#pragma unroll 1
  for (int jt = 0; jt < ITERS; ++jt) {
    const int b = jt & 1;
    const unsigned short* Kc = (const unsigned short*)(smem + b * 9216);
    const unsigned short* Vc = (const unsigned short*)(smem + 18432 + b * 9216);
    const bool more = (jt + 1 < ITERS);

    if (more) {  // global prefetch of next tile into registers
      kr0.s = *(const us8*)(ksrc + (jt + 1) * 4096);
      kr1.s = *(const us8*)(ksrc + (jt + 1) * 4096 + 8);
      vr0.s = *(const us8*)(vsrc + (jt + 1) * 64);
      vr1.s = *(const us8*)(vsrc + (jt + 1) * 64 + 8);
    }

#pragma unroll
    for (int ni = 0; ni < 2; ++ni) {
      // ---- S-phase for keys ni*32..+31 (S^T = K Q^T, cols m = l31)
      V8 ak[4];
#pragma unroll
      for (int kst = 0; kst < 4; ++kst)
        ak[kst].s = *(const us8*)(Kc + (ni * 32 + l31) * 72 + kst * 16 + lh * 8);
      f32x16 sacc;
#pragma unroll
      for (int r = 0; r < 16; ++r) sacc[r] = 0.f;
#pragma unroll
      for (int kst = 0; kst < 4; ++kst)
        sacc = __builtin_amdgcn_mfma_f32_32x32x16_bf16(ak[kst].b, aQ[kst].b,
                                                       sacc, 0, 0, 0);
      // exp2 + pack; pkg[g] = keys ni*32+8g+4lh+{0..3} for q-col l31
      uint2 pkg[4];
#pragma unroll
      for (int g = 0; g < 4; ++g) {
        const float p0 = __builtin_amdgcn_exp2f(sacc[4 * g + 0]);
        const float p1 = __builtin_amdgcn_exp2f(sacc[4 * g + 1]);
        const float p2 = __builtin_amdgcn_exp2f(sacc[4 * g + 2]);
        const float p3 = __builtin_amdgcn_exp2f(sacc[4 * g + 3]);
        lp += (p0 + p1) + (p2 + p3);
        pkg[g].x = pack_bf16x2(p0, p1);
        pkg[g].y = pack_bf16x2(p2, p3);
      }

      // ---- PV-phase for these 32 keys (chunk kst = 2ni+kk)
      V8 bv[2][2];
#pragma unroll
      for (int ci = 0; ci < 2; ++ci)
#pragma unroll
        for (int kk = 0; kk < 2; ++kk)
          bv[ci][kk].s = *(const us8*)(Vc + (ci * 32 + l31) * 72 +
                                       (2 * ni + kk) * 16 + lh * 8);
#pragma unroll
      for (int kk = 0; kk < 2; ++kk) {
        const int gb = 2 * kk;
        const uint2 qa = pkg[gb];      // own quad, g = gb+lh or gb+1-lh
        const uint2 qb2 = pkg[gb + 1];
        uint2 send;  // quad the lane^32 partner needs: g = gb+1-lh
        send.x = lh ? qa.x : qb2.x;
        send.y = lh ? qa.y : qb2.y;
        uint2 recv;
        recv.x = __shfl_xor(send.x, 32);
        recv.y = __shfl_xor(send.y, 32);
        const uint2 keep = {lh ? qb2.x : qa.x, lh ? qb2.y : qa.y};  // g = gb+lh
        V8 ap;  // A-frag lo-quad = 4kst+2lh, hi-quad = 4kst+2lh+1
        ap.u4[0] = lh ? recv.x : keep.x;
        ap.u4[1] = lh ? recv.y : keep.y;
        ap.u4[2] = lh ? keep.x : recv.x;
        ap.u4[3] = lh ? keep.y : recv.y;
        accO[0] = __builtin_amdgcn_mfma_f32_32x32x16_bf16(ap.b, bv[0][kk].b,
                                                          accO[0], 0, 0, 0);
        accO[1] = __builtin_amdgcn_mfma_f32_32x32x16_bf16(ap.b, bv[1][kk].b,
                                                          accO[1], 0, 0, 0);
      }
    }

    if (more) {  // stage next tile into the other buffer; ONE barrier/iter
      unsigned short* kd = (unsigned short*)(smem + (1 - b) * 9216) + soff;
      unsigned short* vd = (unsigned short*)(smem + 18432 + (1 - b) * 9216) + soff;
      *(us8*)kd = kr0.s; *(us8*)(kd + 8) = kr1.s;
      *(us8*)vd = vr0.s; *(us8*)(vd + 8) = vr1.s;
      __syncthreads();
    }
  }

  // l reduce + store (32 q per wave)
  {
    const float lsum = lp + __shfl_xor(lp, 32);
    if (lh == 0)
      Lpart[((size_t)ks * 4 + nb) * HW + qb + w * 32 + l31] = lsum;
  }

  // epilogue: single pass through Otb[64 c][132] bf16 (66-dword row stride
  // -> 2-bank rotation, conflict-free); coalesced us8 stores of [c][128 q].
  __syncthreads();  // all Vc/Kc reads done before smem reuse
#pragma unroll
  for (int ci = 0; ci < 2; ++ci)
#pragma unroll
    for (int r = 0; r < 16; ++r) {
      const int qcol = w * 32 + 8 * (r >> 2) + 4 * lh + (r & 3);
      Otb[(ci * 32 + l31) * 132 + qcol] = f32_to_bf16(accO[ci][r]);
    }
  __syncthreads();
  {
    const int ch = t >> 2, part = t & 3;
    const unsigned short* src = Otb + ch * 132 + part * 32;
    unsigned short* dst =
        Opart + (((size_t)ks * 4 + nb) * 64 + ch) * HW + qb + part * 32;
#pragma unroll
    for (int i = 0; i < 4; ++i) {
      V8 v;
      v.h[0] = *(const us4*)(src + i * 8);
      v.h[1] = *(const us4*)(src + i * 8 + 4);
      *(us8*)(dst + i * 8) = v.s;
    }
  }
}

// ---------------------------------------------------------------------------
// Combine: out[n][c][p] = sum_ks O[ks][n][c][p] / sum_ks l[ks][n][p].
// ---------------------------------------------------------------------------
__global__ __launch_bounds__(256) void combine_kernel(
    const unsigned short* __restrict__ Opart, const float* __restrict__ Lpart,
    float* __restrict__ out) {
  const int tid = blockIdx.x * 256 + threadIdx.x;
  const size_t e = (size_t)tid * 4;
  float4 o = {0.f, 0.f, 0.f, 0.f};
#pragma unroll
  for (int ks = 0; ks < KS; ++ks) {
    const us4 v = *(const us4*)(Opart + (size_t)ks * (4 * 64 * HW) + e);
    o.x += bf16_bits_to_f32(v[0]);
    o.y += bf16_bits_to_f32(v[1]);
    o.z += bf16_bits_to_f32(v[2]);
    o.w += bf16_bits_to_f32(v[3]);
  }
  const int n = (int)(e / (64 * HW));
  const int p = (int)(e % HW);
  float4 l = {0.f, 0.f, 0.f, 0.f};
#pragma unroll
  for (int ks = 0; ks < KS; ++ks) {
    const float4 v = *(const float4*)(Lpart + ((size_t)ks * 4 + n) * HW + p);
    l.x += v.x; l.y += v.y; l.z += v.z; l.w += v.w;
  }
  float4 r;
  r.x = o.x / l.x; r.y = o.y / l.y; r.z = o.z / l.z; r.w = o.w / l.w;
  *(float4*)(out + e) = r;
}

extern "C" void kernel_launch(void* const* d_in, const int* in_sizes, int n_in,
                              void* d_out, int out_size, void* d_ws, size_t ws_size,
                              hipStream_t stream) {
  const float* x = (const float*)d_in[0];
  const float* w1 = (const float*)d_in[1];
  const float* b1 = (const float*)d_in[2];
  const float* w2 = (const float*)d_in[3];
  const float* b2 = (const float*)d_in[4];
  const float* w3 = (const float*)d_in[5];
  const float* b3 = (const float*)d_in[6];
  float* out = (float*)d_out;

  // ws: Q,K,V bf16 (9.8 MB) + Opart bf16 KS=5 (16.4 MB) + Lpart (0.5 MB)
  unsigned short* Q = (unsigned short*)d_ws;
  unsigned short* K = Q + (size_t)4 * HW * 64;
  unsigned short* V = K + (size_t)4 * HW * 64;
  unsigned short* Opart = V + (size_t)4 * HW * 64;
  float* Lpart = (float*)(Opart + (size_t)KS * 4 * 64 * HW);

  conv_kernel<<<dim3(50, 4), 256, 0, stream>>>(x, w1, b1, w2, b2, w3, b3,
                                               Q, K, V);
  attn_kernel<<<dim3(50, 4, KS), 256, 0, stream>>>(Q, K, V, Opart, Lpart);
  combine_kernel<<<1600, 256, 0, stream>>>(Opart, Lpart, out);
}